// Round 2
// 314.577 us; speedup vs baseline: 1.1645x; 1.1645x over previous
//
#include <hip/hip_runtime.h>

// relu(x @ W^T + b): M=131072, K=256, N=256, f32 in/out.
// R6 == R5 resubmitted: previous round died on container acquisition
// (infra), no kernel signal. Source audited for crash modes: no OOB
// (max rows/cols/k all exactly at bounds), no barriers, no loops that
// can hang. Resubmitting unchanged to collect counters.
//
// R5: split-bf16 MFMA. Each f32 operand is decomposed as hi+lo bf16
// (truncation split); out = xh*wh + xh*wl + xl*wh accumulated in fp32
// MFMA accumulators -> ~1e-4 absmax vs fp32 reference.
//
// Layout-bug de-risking vs the 3 failed MFMA rounds:
//  - A and B fragments are loaded with the SAME per-lane k rule
//    (row = lane&31, k = kstep*16 + (lane>>5)*8 + j). Any internal HW
//    k-permutation cancels in the dot product (sum over k is order-free).
//  - C/D mapping is the HW-verified one (learn_hip m74/m101):
//    col = lane&31, row = (reg&3) + 8*(reg>>2) + 4*(lane>>5).
//  - No LDS, no staging, no syncthreads: fragments come per-lane from
//    global (W is 256KB L2-resident; x streamed once, 128B-line coalesced).
//
// Structure: 128x128 block tile, 4 waves (2x2), each wave 64x64 as 2x2
// fragments of 32x32x16 bf16 MFMA; K=256 in 16 steps with 1-deep register
// prefetch; fused bias+ReLU epilogue with coalesced dword stores.

#define BM 128
#define BN 128

typedef __attribute__((ext_vector_type(16))) float f32x16;
typedef __attribute__((ext_vector_type(8))) __bf16 bf16x8;

// Truncation split of 8 f32 into hi/lo bf16x8 fragments.
// hi = top 16 bits of f; lo = trunc16(f - hi). Dropped mass ~2^-16 rel.
__device__ __forceinline__ void cvt8(const float4& A, const float4& B,
                                     bf16x8& hi, bf16x8& lo) {
    const float f[8] = {A.x, A.y, A.z, A.w, B.x, B.y, B.z, B.w};
#pragma unroll
    for (int j = 0; j < 8; ++j) {
        const unsigned int u = __builtin_bit_cast(unsigned int, f[j]);
        hi[j] = __builtin_bit_cast(__bf16, (unsigned short)(u >> 16));
        const float hf = __builtin_bit_cast(float, u & 0xffff0000u);
        const float lf = f[j] - hf;
        lo[j] = __builtin_bit_cast(__bf16,
                    (unsigned short)(__builtin_bit_cast(unsigned int, lf) >> 16));
    }
}

#define MFMA(a, b, c) \
    (c) = __builtin_amdgcn_mfma_f32_32x32x16_bf16((a), (b), (c), 0, 0, 0)

__global__ __launch_bounds__(256)
void gemm_mfma_kernel(const float* __restrict__ x,
                      const float* __restrict__ W,
                      const float* __restrict__ bias,
                      float* __restrict__ out) {
    const int tid  = threadIdx.x;
    const int lane = tid & 63;
    const int wid  = tid >> 6;          // 0..3
    const int wm   = wid >> 1;          // wave row 0/1
    const int wn   = wid & 1;           // wave col 0/1
    const int rt   = (int)(blockIdx.x >> 1);
    const int ct   = (int)(blockIdx.x & 1);

    const int r31 = lane & 31;          // row/col within a 32-fragment
    const int g   = lane >> 5;          // k-group 0/1 (8 k each)

    // Fragment source pointers. A from x[m][k]; B from W[n][k] (W == B^T,
    // so the addressing rule is identical to A's -> k-permutation cancels).
    const long arow = (long)rt * BM + wm * 64 + r31;
    const int  bcol = ct * BN + wn * 64 + r31;
    const float* ap0 = x + arow * 256 + g * 8;          // A frag i=0
    const float* ap1 = ap0 + 32 * 256;                  // A frag i=1
    const float* bp0 = W + (long)bcol * 256 + g * 8;    // B frag j=0
    const float* bp1 = bp0 + 32 * 256;                  // B frag j=1

    f32x16 acc[2][2];
#pragma unroll
    for (int i = 0; i < 2; ++i)
#pragma unroll
        for (int j = 0; j < 2; ++j)
#pragma unroll
            for (int r = 0; r < 16; ++r) acc[i][j][r] = 0.f;

    // Prologue: load k-step 0 fragments (f32).
    float4 a0A = *(const float4*)(ap0);
    float4 a0B = *(const float4*)(ap0 + 4);
    float4 a1A = *(const float4*)(ap1);
    float4 a1B = *(const float4*)(ap1 + 4);
    float4 b0A = *(const float4*)(bp0);
    float4 b0B = *(const float4*)(bp0 + 4);
    float4 b1A = *(const float4*)(bp1);
    float4 b1B = *(const float4*)(bp1 + 4);

#pragma unroll
    for (int t = 0; t < 16; ++t) {      // k-step = 16, K = 256
        bf16x8 ah0, al0, ah1, al1, bh0, bl0, bh1, bl1;
        cvt8(a0A, a0B, ah0, al0);
        cvt8(a1A, a1B, ah1, al1);
        cvt8(b0A, b0B, bh0, bl0);
        cvt8(b1A, b1B, bh1, bl1);

        if (t < 15) {                   // 1-deep register prefetch
            const int o = (t + 1) * 16;
            a0A = *(const float4*)(ap0 + o);
            a0B = *(const float4*)(ap0 + o + 4);
            a1A = *(const float4*)(ap1 + o);
            a1B = *(const float4*)(ap1 + o + 4);
            b0A = *(const float4*)(bp0 + o);
            b0B = *(const float4*)(bp0 + o + 4);
            b1A = *(const float4*)(bp1 + o);
            b1B = *(const float4*)(bp1 + o + 4);
        }

        // hh products
        MFMA(ah0, bh0, acc[0][0]); MFMA(ah0, bh1, acc[0][1]);
        MFMA(ah1, bh0, acc[1][0]); MFMA(ah1, bh1, acc[1][1]);
        // hl products
        MFMA(ah0, bl0, acc[0][0]); MFMA(ah0, bl1, acc[0][1]);
        MFMA(ah1, bl0, acc[1][0]); MFMA(ah1, bl1, acc[1][1]);
        // lh products
        MFMA(al0, bh0, acc[0][0]); MFMA(al0, bh1, acc[0][1]);
        MFMA(al1, bh0, acc[1][0]); MFMA(al1, bh1, acc[1][1]);
    }

    // Epilogue: bias + ReLU. C/D map (verified m74/m101):
    // col = lane&31, row = (r&3) + 8*(r>>2) + 4*(lane>>5).
    const int  ocol0 = ct * BN + wn * 64;
    const long orow0 = (long)rt * BM + wm * 64;
    const float bj0 = bias[ocol0 + r31];
    const float bj1 = bias[ocol0 + 32 + r31];

#pragma unroll
    for (int i = 0; i < 2; ++i) {
#pragma unroll
        for (int r = 0; r < 16; ++r) {
            const int rowf = (r & 3) + 8 * (r >> 2) + 4 * g;
            const long row = orow0 + i * 32 + rowf;
            float v0 = acc[i][0][r] + bj0;
            float v1 = acc[i][1][r] + bj1;
            v0 = v0 > 0.f ? v0 : 0.f;
            v1 = v1 > 0.f ? v1 : 0.f;
            out[row * 256 + ocol0 + r31]      = v0;
            out[row * 256 + ocol0 + 32 + r31] = v1;
        }
    }
}

extern "C" void kernel_launch(void* const* d_in, const int* in_sizes, int n_in,
                              void* d_out, int out_size, void* d_ws, size_t ws_size,
                              hipStream_t stream) {
    (void)n_in; (void)d_ws; (void)ws_size; (void)out_size;
    const float* x = (const float*)d_in[0];
    const float* W = (const float*)d_in[1];
    const float* b = (const float*)d_in[2];
    float* out = (float*)d_out;

    const int M = in_sizes[0] / 256;     // 131072
    const int grid = (M / BM) * 2;       // 1024 row-tiles x 2 col-tiles = 2048

    gemm_mfma_kernel<<<grid, 256, 0, stream>>>(x, W, b, out);
}

// Round 3
// 262.023 us; speedup vs baseline: 1.3981x; 1.2006x over previous
//
#include <hip/hip_runtime.h>

// relu(x @ W^T + b): M=131072, K=256, N=256, f32 in/out.
// R7: fix the latency/issue bottleneck found in R6 counters (MfmaUtil 12.5%,
// VALUBusy 17%, HBM 21% -> everything idle; per-lane scattered fragment loads
// serialize the TA on 32-line requests).
//  - W (256 KB) pre-converted ONCE by a prologue kernel into d_ws as hi/lo
//    bf16 in exact B-fragment order -> hot-loop B loads are dense 1KB,
//    L2-resident, no W cvt in the loop.
//  - x staged f32 into LDS via global_load_lds width=16 (dense), BK=32,
//    double-buffered, T3 2-phase schedule.
//  - Both-sides XOR swizzle (granule c ^= m&7): linear LDS dest + swizzled
//    per-lane GLOBAL source (m173 pattern), same XOR on ds_read_b128.
//  - XCD-aware blockIdx swizzle (nwg=2048 divisible by 8).
// Math/epilogue identical to verified R6 (absmax 0.0156 pass):
// out = xh*wh + xh*wl + xl*wh via mfma_f32_32x32x16_bf16, fp32 acc.

typedef __attribute__((ext_vector_type(16))) float f32x16;
typedef __attribute__((ext_vector_type(8))) __bf16 bf16x8;

#define MFMA(a, b, c) \
    (c) = __builtin_amdgcn_mfma_f32_32x32x16_bf16((a), (b), (c), 0, 0, 0)

// Truncation split of 8 f32 into hi/lo bf16x8 fragments.
__device__ __forceinline__ void cvt8(const float4& A, const float4& B,
                                     bf16x8& hi, bf16x8& lo) {
    const float f[8] = {A.x, A.y, A.z, A.w, B.x, B.y, B.z, B.w};
#pragma unroll
    for (int j = 0; j < 8; ++j) {
        const unsigned int u = __builtin_bit_cast(unsigned int, f[j]);
        hi[j] = __builtin_bit_cast(__bf16, (unsigned short)(u >> 16));
        const float hf = __builtin_bit_cast(float, u & 0xffff0000u);
        const float lf = f[j] - hf;
        lo[j] = __builtin_bit_cast(__bf16,
                    (unsigned short)(__builtin_bit_cast(unsigned int, lf) >> 16));
    }
}

__device__ __forceinline__ void gload16(const float* g, float* l) {
    __builtin_amdgcn_global_load_lds(
        (const __attribute__((address_space(1))) void*)g,
        (__attribute__((address_space(3))) void*)l, 16, 0, 0);
}

// ---------------- W prep: f32 -> hi/lo bf16 in B-fragment order -------------
// chunk f = (ct*4 + wn*2 + j)*16 + t  (f = 0..127), 1 wave per chunk.
// lane l holds n = ct*128+wn*64+j*32+(l&31), k = t*16+(l>>5)*8 .. +7.
__global__ __launch_bounds__(256)
void wprep_kernel(const float* __restrict__ W,
                  __bf16* __restrict__ whi, __bf16* __restrict__ wlo) {
    const int wv = (int)blockIdx.x * 4 + (threadIdx.x >> 6);   // 0..127
    const int l  = threadIdx.x & 63;
    const int t  = wv & 15;
    const int j  = (wv >> 4) & 1;
    const int wn = (wv >> 5) & 1;
    const int ct = wv >> 6;
    const int n  = ct * 128 + wn * 64 + j * 32 + (l & 31);
    const int k  = t * 16 + (l >> 5) * 8;
    const float4 A = *(const float4*)(W + n * 256 + k);
    const float4 B = *(const float4*)(W + n * 256 + k + 4);
    bf16x8 hi, lo;
    cvt8(A, B, hi, lo);
    *(bf16x8*)(whi + wv * 512 + l * 8) = hi;
    *(bf16x8*)(wlo + wv * 512 + l * 8) = lo;
}

// ---------------- main GEMM -------------------------------------------------
__global__ __launch_bounds__(256)
void gemm_mfma_kernel(const float* __restrict__ x,
                      const __bf16* __restrict__ whi,
                      const __bf16* __restrict__ wlo,
                      const float* __restrict__ bias,
                      float* __restrict__ out) {
    // 2 buffers x 128 rows x 32 f32 (8 granules of 16B per row)
    __shared__ float xs[2][4096];

    const int tid  = threadIdx.x;
    const int lane = tid & 63;
    const int wid  = tid >> 6;
    const int wm   = wid >> 1;
    const int wn   = wid & 1;

    // XCD swizzle: 2048 blocks, 8 XCDs -> each XCD a contiguous swz range.
    const int bid = (int)blockIdx.x;
    const int swz = (bid & 7) * 256 + (bid >> 3);
    const int rt  = swz >> 1;
    const int ct  = swz & 1;

    const int r31 = lane & 31;
    const int g   = lane >> 5;
    const long row0 = (long)rt * 128;

    const int Gbase = wid * 64 + lane;      // staging granule id base
    const int m0 = wm * 64 + r31;           // A frag i=0 row in tile
    const int m1 = m0 + 32;                 // A frag i=1 row
    const int sw = r31 & 7;                 // read-side XOR (m&7, same for m0/m1)

    f32x16 acc[2][2];
#pragma unroll
    for (int i = 0; i < 2; ++i)
#pragma unroll
        for (int j = 0; j < 2; ++j)
#pragma unroll
            for (int r = 0; r < 16; ++r) acc[i][j][r] = 0.f;

    const int fbase0 = (ct * 4 + wn * 2) * 16;   // B chunk base, j=0
    const __bf16* whip = whi + (long)lane * 8;
    const __bf16* wlop = wlo + (long)lane * 8;

    // Stage one BK=32 chunk into buffer b. Linear LDS dest, swizzled source.
    auto STAGE = [&](int b, int chunk) {
#pragma unroll
        for (int j = 0; j < 4; ++j) {
            const int G = j * 256 + Gbase;           // 0..1023
            const int m = G >> 3;                    // tile row 0..127
            const int cs = (G & 7) ^ (m & 7);        // swizzled source granule
            const float* gp = x + (row0 + m) * 256 + chunk * 32 + cs * 4;
            float* lp = &xs[b][(j * 256 + wid * 64) * 4];   // wave-uniform base
            gload16(gp, lp);
        }
    };

    auto COMPUTE = [&](int b, int chunk) {
#pragma unroll
        for (int t = 0; t < 2; ++t) {
            const int ks = chunk * 2 + t;            // global k-step 0..15
            const int c0 = t * 4 + g * 2;            // granule pair base
            const float* xb = &xs[b][0];
            const float4 A0a = *(const float4*)(xb + m0 * 32 + ((c0 ^ sw) * 4));
            const float4 A0b = *(const float4*)(xb + m0 * 32 + (((c0 + 1) ^ sw) * 4));
            const float4 A1a = *(const float4*)(xb + m1 * 32 + ((c0 ^ sw) * 4));
            const float4 A1b = *(const float4*)(xb + m1 * 32 + (((c0 + 1) ^ sw) * 4));
            bf16x8 ah0, al0, ah1, al1;
            cvt8(A0a, A0b, ah0, al0);
            cvt8(A1a, A1b, ah1, al1);

            const long f0 = (long)(fbase0 + ks) * 512;
            const long f1 = f0 + 16 * 512;
            const bf16x8 bh0 = *(const bf16x8*)(whip + f0);
            const bf16x8 bl0 = *(const bf16x8*)(wlop + f0);
            const bf16x8 bh1 = *(const bf16x8*)(whip + f1);
            const bf16x8 bl1 = *(const bf16x8*)(wlop + f1);

            MFMA(ah0, bh0, acc[0][0]); MFMA(ah0, bh1, acc[0][1]);
            MFMA(ah1, bh0, acc[1][0]); MFMA(ah1, bh1, acc[1][1]);
            MFMA(ah0, bl0, acc[0][0]); MFMA(ah0, bl1, acc[0][1]);
            MFMA(ah1, bl0, acc[1][0]); MFMA(ah1, bl1, acc[1][1]);
            MFMA(al0, bh0, acc[0][0]); MFMA(al0, bh1, acc[0][1]);
            MFMA(al1, bh0, acc[1][0]); MFMA(al1, bh1, acc[1][1]);
        }
    };

    STAGE(0, 0);
    asm volatile("s_waitcnt vmcnt(0)" ::: "memory");
    __syncthreads();
    for (int c = 0; c < 7; ++c) {
        STAGE((c + 1) & 1, c + 1);
        COMPUTE(c & 1, c);
        asm volatile("s_waitcnt vmcnt(0)" ::: "memory");
        __syncthreads();
    }
    COMPUTE(1, 7);

    // Epilogue: bias + ReLU. C/D map (verified m74/m101):
    // col = lane&31, row = (r&3) + 8*(r>>2) + 4*(lane>>5).
    const int  ocol0 = ct * 128 + wn * 64;
    const long orow0 = (long)rt * 128 + wm * 64;
    const float bj0 = bias[ocol0 + r31];
    const float bj1 = bias[ocol0 + 32 + r31];

#pragma unroll
    for (int i = 0; i < 2; ++i) {
#pragma unroll
        for (int r = 0; r < 16; ++r) {
            const int rowf = (r & 3) + 8 * (r >> 2) + 4 * g;
            const long row = orow0 + i * 32 + rowf;
            float v0 = acc[i][0][r] + bj0;
            float v1 = acc[i][1][r] + bj1;
            v0 = v0 > 0.f ? v0 : 0.f;
            v1 = v1 > 0.f ? v1 : 0.f;
            out[row * 256 + ocol0 + r31]      = v0;
            out[row * 256 + ocol0 + 32 + r31] = v1;
        }
    }
}

extern "C" void kernel_launch(void* const* d_in, const int* in_sizes, int n_in,
                              void* d_out, int out_size, void* d_ws, size_t ws_size,
                              hipStream_t stream) {
    (void)n_in; (void)ws_size; (void)out_size;
    const float* x = (const float*)d_in[0];
    const float* W = (const float*)d_in[1];
    const float* b = (const float*)d_in[2];
    float* out = (float*)d_out;

    __bf16* whi = (__bf16*)d_ws;             // 65536 elems = 128 KB
    __bf16* wlo = whi + 65536;               // 65536 elems = 128 KB

    wprep_kernel<<<32, 256, 0, stream>>>(W, whi, wlo);

    const int M = in_sizes[0] / 256;         // 131072
    const int grid = (M / 128) * 2;          // 2048
    gemm_mfma_kernel<<<grid, 256, 0, stream>>>(x, whi, wlo, b, out);
}

// Round 4
// 256.008 us; speedup vs baseline: 1.4309x; 1.0235x over previous
//
#include <hip/hip_runtime.h>

// relu(x @ W^T + b): M=131072, K=256, N=256, f32 in/out.
// R8: kill the per-chunk full drain found in R7 counters (all pipes <25%
// busy, 104 us vs ~32 us memory floor -> latency-bound 2-phase schedule).
// T3/T4 minimum form:
//  - 3 LDS buffers (48 KB), 2-deep global_load_lds prefetch.
//  - per chunk: s_waitcnt vmcnt(4) -> raw s_barrier (NO compiler drain)
//    -> B-loads (L2) -> STAGE(c+2) -> ds_read+cvt+MFMA. Never vmcnt(0)
//    in the main loop.
//  - B-loads issued BEFORE STAGE(c+2) (sched_barrier(0) pins order) so
//    consuming B does not force-drain the newest prefetch (vmcnt waits
//    oldest-first).
// Math identical to verified R7 (absmax 0.015625): W pre-split to hi/lo
// bf16 fragment-order by wprep; x staged f32 with both-sides XOR swizzle;
// out = xh*wh + xh*wl + xl*wh via mfma_f32_32x32x16_bf16, fp32 acc.

typedef __attribute__((ext_vector_type(16))) float f32x16;
typedef __attribute__((ext_vector_type(8))) __bf16 bf16x8;

#define MFMA(a, b, c) \
    (c) = __builtin_amdgcn_mfma_f32_32x32x16_bf16((a), (b), (c), 0, 0, 0)

// Truncation split of 8 f32 into hi/lo bf16x8 fragments (verified R6/R7).
__device__ __forceinline__ void cvt8(const float4& A, const float4& B,
                                     bf16x8& hi, bf16x8& lo) {
    const float f[8] = {A.x, A.y, A.z, A.w, B.x, B.y, B.z, B.w};
#pragma unroll
    for (int j = 0; j < 8; ++j) {
        const unsigned int u = __builtin_bit_cast(unsigned int, f[j]);
        hi[j] = __builtin_bit_cast(__bf16, (unsigned short)(u >> 16));
        const float hf = __builtin_bit_cast(float, u & 0xffff0000u);
        const float lf = f[j] - hf;
        lo[j] = __builtin_bit_cast(__bf16,
                    (unsigned short)(__builtin_bit_cast(unsigned int, lf) >> 16));
    }
}

__device__ __forceinline__ void gload16(const float* g, float* l) {
    __builtin_amdgcn_global_load_lds(
        (const __attribute__((address_space(1))) void*)g,
        (__attribute__((address_space(3))) void*)l, 16, 0, 0);
}

// ---------------- W prep: f32 -> hi/lo bf16 in B-fragment order -------------
__global__ __launch_bounds__(256)
void wprep_kernel(const float* __restrict__ W,
                  __bf16* __restrict__ whi, __bf16* __restrict__ wlo) {
    const int wv = (int)blockIdx.x * 4 + (threadIdx.x >> 6);   // 0..127
    const int l  = threadIdx.x & 63;
    const int t  = wv & 15;
    const int j  = (wv >> 4) & 1;
    const int wn = (wv >> 5) & 1;
    const int ct = wv >> 6;
    const int n  = ct * 128 + wn * 64 + j * 32 + (l & 31);
    const int k  = t * 16 + (l >> 5) * 8;
    const float4 A = *(const float4*)(W + n * 256 + k);
    const float4 B = *(const float4*)(W + n * 256 + k + 4);
    bf16x8 hi, lo;
    cvt8(A, B, hi, lo);
    *(bf16x8*)(whi + wv * 512 + l * 8) = hi;
    *(bf16x8*)(wlo + wv * 512 + l * 8) = lo;
}

// ---------------- main GEMM -------------------------------------------------
__global__ __launch_bounds__(256)
void gemm_mfma_kernel(const float* __restrict__ x,
                      const __bf16* __restrict__ whi,
                      const __bf16* __restrict__ wlo,
                      const float* __restrict__ bias,
                      float* __restrict__ out) {
    // 3 buffers x 128 rows x 32 f32 = 48 KB
    __shared__ float xs[3][4096];

    const int tid  = threadIdx.x;
    const int lane = tid & 63;
    const int wid  = tid >> 6;
    const int wm   = wid >> 1;
    const int wn   = wid & 1;

    // XCD swizzle: 2048 blocks, 8 XCDs; rt-pairs (ct=0/1) land on same XCD.
    const int bid = (int)blockIdx.x;
    const int swz = (bid & 7) * 256 + (bid >> 3);
    const int rt  = swz >> 1;
    const int ct  = swz & 1;

    const int r31 = lane & 31;
    const int g   = lane >> 5;
    const long row0 = (long)rt * 128;

    const int Gbase = wid * 64 + lane;
    const int m0 = wm * 64 + r31;
    const int m1 = m0 + 32;
    const int sw = r31 & 7;

    f32x16 acc[2][2];
#pragma unroll
    for (int i = 0; i < 2; ++i)
#pragma unroll
        for (int j = 0; j < 2; ++j)
#pragma unroll
            for (int r = 0; r < 16; ++r) acc[i][j][r] = 0.f;

    const int fbase0 = (ct * 4 + wn * 2) * 16;
    const __bf16* whip = whi + (long)lane * 8;
    const __bf16* wlop = wlo + (long)lane * 8;

    // Stage one BK=32 chunk into buffer b. Linear LDS dest, swizzled source.
    auto STAGE = [&](int b, int chunk) {
#pragma unroll
        for (int j = 0; j < 4; ++j) {
            const int G = j * 256 + Gbase;
            const int m = G >> 3;
            const int cs = (G & 7) ^ (m & 7);
            const float* gp = x + (row0 + m) * 256 + chunk * 32 + cs * 4;
            float* lp = &xs[b][(j * 256 + wid * 64) * 4];
            gload16(gp, lp);
        }
    };

    // One t-step (k-width 16) of MFMA work from buffer b.
    auto TSTEP = [&](const float* xb, int t,
                     const bf16x8& bh0, const bf16x8& bl0,
                     const bf16x8& bh1, const bf16x8& bl1) {
        const int c0 = t * 4 + g * 2;
        const float4 A0a = *(const float4*)(xb + m0 * 32 + ((c0 ^ sw) * 4));
        const float4 A0b = *(const float4*)(xb + m0 * 32 + (((c0 + 1) ^ sw) * 4));
        const float4 A1a = *(const float4*)(xb + m1 * 32 + ((c0 ^ sw) * 4));
        const float4 A1b = *(const float4*)(xb + m1 * 32 + (((c0 + 1) ^ sw) * 4));
        bf16x8 ah0, al0, ah1, al1;
        cvt8(A0a, A0b, ah0, al0);
        cvt8(A1a, A1b, ah1, al1);
        MFMA(ah0, bh0, acc[0][0]); MFMA(ah0, bh1, acc[0][1]);
        MFMA(ah1, bh0, acc[1][0]); MFMA(ah1, bh1, acc[1][1]);
        MFMA(ah0, bl0, acc[0][0]); MFMA(ah0, bl1, acc[0][1]);
        MFMA(ah1, bl0, acc[1][0]); MFMA(ah1, bl1, acc[1][1]);
        MFMA(al0, bh0, acc[0][0]); MFMA(al0, bh1, acc[0][1]);
        MFMA(al1, bh0, acc[1][0]); MFMA(al1, bh1, acc[1][1]);
    };

    // Per-chunk phase. VM is the vmcnt immediate as a string literal.
    // Order: wait(buf c ready, keep newer in flight) -> raw barrier ->
    // B-loads (older than next STAGE!) -> STAGE(c+2) -> compute.
#define CHUNK(c, VM)                                                          \
    {                                                                         \
        asm volatile("s_waitcnt vmcnt(" VM ")" ::: "memory");                 \
        __builtin_amdgcn_s_barrier();                                         \
        const long f0 = (long)(fbase0 + (c) * 2) * 512;                       \
        const long f1 = f0 + 16 * 512;                                        \
        const long h0 = (long)(fbase0 + (c) * 2 + 1) * 512;                   \
        const long h1 = h0 + 16 * 512;                                        \
        const bf16x8 B0h0 = *(const bf16x8*)(whip + f0);                      \
        const bf16x8 B0l0 = *(const bf16x8*)(wlop + f0);                      \
        const bf16x8 B0h1 = *(const bf16x8*)(whip + f1);                      \
        const bf16x8 B0l1 = *(const bf16x8*)(wlop + f1);                      \
        const bf16x8 B1h0 = *(const bf16x8*)(whip + h0);                      \
        const bf16x8 B1l0 = *(const bf16x8*)(wlop + h0);                      \
        const bf16x8 B1h1 = *(const bf16x8*)(whip + h1);                      \
        const bf16x8 B1l1 = *(const bf16x8*)(wlop + h1);                      \
        __builtin_amdgcn_sched_barrier(0);                                    \
        if ((c) + 2 < 8) STAGE(((c) + 2) % 3, (c) + 2);                       \
        const float* xb = &xs[(c) % 3][0];                                    \
        TSTEP(xb, 0, B0h0, B0l0, B0h1, B0l1);                                 \
        TSTEP(xb, 1, B1h0, B1l0, B1h1, B1l1);                                 \
    }

    STAGE(0, 0);
    STAGE(1, 1);
    CHUNK(0, "4")
    CHUNK(1, "4")
    CHUNK(2, "4")
    CHUNK(3, "4")
    CHUNK(4, "4")
    CHUNK(5, "4")
    CHUNK(6, "4")
    CHUNK(7, "0")
#undef CHUNK

    // Epilogue: bias + ReLU. C/D map (verified m74/m101):
    // col = lane&31, row = (r&3) + 8*(r>>2) + 4*(lane>>5).
    const int  ocol0 = ct * 128 + wn * 64;
    const long orow0 = (long)rt * 128 + wm * 64;
    const float bj0 = bias[ocol0 + r31];
    const float bj1 = bias[ocol0 + 32 + r31];

#pragma unroll
    for (int i = 0; i < 2; ++i) {
#pragma unroll
        for (int r = 0; r < 16; ++r) {
            const int rowf = (r & 3) + 8 * (r >> 2) + 4 * g;
            const long row = orow0 + i * 32 + rowf;
            float v0 = acc[i][0][r] + bj0;
            float v1 = acc[i][1][r] + bj1;
            v0 = v0 > 0.f ? v0 : 0.f;
            v1 = v1 > 0.f ? v1 : 0.f;
            out[row * 256 + ocol0 + r31]      = v0;
            out[row * 256 + ocol0 + 32 + r31] = v1;
        }
    }
}

extern "C" void kernel_launch(void* const* d_in, const int* in_sizes, int n_in,
                              void* d_out, int out_size, void* d_ws, size_t ws_size,
                              hipStream_t stream) {
    (void)n_in; (void)ws_size; (void)out_size;
    const float* x = (const float*)d_in[0];
    const float* W = (const float*)d_in[1];
    const float* b = (const float*)d_in[2];
    float* out = (float*)d_out;

    __bf16* whi = (__bf16*)d_ws;             // 128 KB
    __bf16* wlo = whi + 65536;               // 128 KB

    wprep_kernel<<<32, 256, 0, stream>>>(W, whi, wlo);

    const int M = in_sizes[0] / 256;         // 131072
    const int grid = (M / 128) * 2;          // 2048
    gemm_mfma_kernel<<<grid, 256, 0, stream>>>(x, whi, wlo, b, out);
}